// Round 7
// baseline (281.688 us; speedup 1.0000x reference)
//
#include <hip/hip_runtime.h>
#include <hip/hip_fp16.h>

#define N_NODES 100000
#define F_IN 128
#define H 16
#define NBIN 391           // ceil(N_NODES/256); bin b owns nodes [b*256, b*256+256)
#define BINCAP 4608        // per-bin record capacity (mean 4096, +8 sigma)
#define ECHUNK 4096        // edges per binfill block

// ---------------------------------------------------------------------------
// k_init: binCur[b] = b * BINCAP  (record-region cursors)
// ---------------------------------------------------------------------------
__global__ void __launch_bounds__(512) k_init(int* __restrict__ binCur) {
  int t = threadIdx.x;
  if (t < NBIN) binCur[t] = t * BINCAP;
}

// ---------------------------------------------------------------------------
// k_lin1 (v2): y1l = fp16(x @ W1l), y1r = x @ W1r (fp32).
// 8 threads per node: part 0-3 -> W1l float4 channel-group, 4-7 -> W1r.
// Grid = 3125 blocks (vs 391 thread-per-node) -> ~12 waves/SIMD, fixing the
// 14% occupancy latency stall seen in R6. x float4 is broadcast across the
// 8 lanes of a node (1 line fetch); W float4s come from L1 (16 KB total).
// ---------------------------------------------------------------------------
__global__ void __launch_bounds__(256) k_lin1(
    const float* __restrict__ x, const float* __restrict__ W1l,
    const float* __restrict__ W1r, __half* __restrict__ y1l,
    float* __restrict__ y1r) {
  int t = blockIdx.x * 256 + threadIdx.x;
  int n = t >> 3;
  if (n >= N_NODES) return;
  int part = t & 7;
  const float* W = (part < 4) ? W1l : W1r;
  int cg = (part & 3) * 4;              // channel group start
  const float4* xr = (const float4*)(x + (size_t)n * F_IN);
  float4 acc = make_float4(0.f, 0.f, 0.f, 0.f);
  // 2-deep prefetch on the x stream
  float4 x0 = xr[0];
  float4 x1 = xr[1];
  for (int k4 = 0; k4 < F_IN / 4; ++k4) {
    float4 cur = x0;
    x0 = x1;
    if (k4 + 2 < F_IN / 4) x1 = xr[k4 + 2];
    int kbase = k4 * 4;
    float4 w0 = *(const float4*)(W + (kbase + 0) * H + cg);
    float4 w1 = *(const float4*)(W + (kbase + 1) * H + cg);
    float4 w2 = *(const float4*)(W + (kbase + 2) * H + cg);
    float4 w3 = *(const float4*)(W + (kbase + 3) * H + cg);
    acc.x = fmaf(cur.x, w0.x, acc.x); acc.y = fmaf(cur.x, w0.y, acc.y);
    acc.z = fmaf(cur.x, w0.z, acc.z); acc.w = fmaf(cur.x, w0.w, acc.w);
    acc.x = fmaf(cur.y, w1.x, acc.x); acc.y = fmaf(cur.y, w1.y, acc.y);
    acc.z = fmaf(cur.y, w1.z, acc.z); acc.w = fmaf(cur.y, w1.w, acc.w);
    acc.x = fmaf(cur.z, w2.x, acc.x); acc.y = fmaf(cur.z, w2.y, acc.y);
    acc.z = fmaf(cur.z, w2.z, acc.z); acc.w = fmaf(cur.z, w2.w, acc.w);
    acc.x = fmaf(cur.w, w3.x, acc.x); acc.y = fmaf(cur.w, w3.y, acc.y);
    acc.z = fmaf(cur.w, w3.z, acc.z); acc.w = fmaf(cur.w, w3.w, acc.w);
  }
  if (part < 4) {
    __half2 h0 = __floats2half2_rn(acc.x, acc.y);
    __half2 h1 = __floats2half2_rn(acc.z, acc.w);
    uint2 pk;
    pk.x = *(unsigned int*)&h0;
    pk.y = *(unsigned int*)&h1;
    *(uint2*)(y1l + (size_t)n * H + cg) = pk;       // 8 B store
  } else {
    *(float4*)(y1r + (size_t)n * H + cg) = acc;     // 16 B store
  }
}

// ---------------------------------------------------------------------------
// k_binfill: radix pass 1 — bin records (src<<8 | dstLow) by dst>>8.
// Per-block LDS histogram, one global cursor atomicAdd per (block,bin),
// then ranged (sequential) writes: ~2 writers per 64B line, low write amp.
// Record ORDER in a bin is nondeterministic (atomic races) but the record
// SET is deterministic; k_binsort canonicalizes the order.
// ---------------------------------------------------------------------------
__global__ void __launch_bounds__(512) k_binfill(
    const int* __restrict__ src, const int* __restrict__ dst,
    int* __restrict__ binCur, int* __restrict__ recs, int E) {
  __shared__ int hist[512];
  __shared__ int gbase[512];
  __shared__ int cnt2[512];
  int t = threadIdx.x;
  hist[t] = 0;
  cnt2[t] = 0;
  __syncthreads();
  int base = blockIdx.x * ECHUNK;
  int rec[8], bin[8];
#pragma unroll
  for (int j = 0; j < 8; ++j) {
    int e = base + j * 512 + t;
    if (e < E) {
      int s = src[e];
      int d = dst[e];
      rec[j] = (s << 8) | (d & 255);
      bin[j] = d >> 8;
      atomicAdd(&hist[bin[j]], 1);
    } else {
      bin[j] = -1;
    }
  }
  __syncthreads();
  if (t < NBIN) {
    int c = hist[t];
    gbase[t] = (c > 0) ? atomicAdd(&binCur[t], c) : 0;
  }
  __syncthreads();
#pragma unroll
  for (int j = 0; j < 8; ++j) {
    if (bin[j] >= 0) {
      int loc = atomicAdd(&cnt2[bin[j]], 1);
      int slot = gbase[bin[j]] + loc;
      if (slot < (bin[j] + 1) * BINCAP)  // safety clamp (never expected)
        recs[slot] = rec[j];
    }
  }
}

// ---------------------------------------------------------------------------
// k_binsort: radix pass 2 — one block per bin. Canonical rank-sort within
// each row makes the CSR (and thus all fp summation orders) bitwise
// deterministic run-to-run.
// ---------------------------------------------------------------------------
__global__ void __launch_bounds__(512) k_binsort(
    int* __restrict__ recs, const int* __restrict__ binCur,
    int* __restrict__ deg, int* __restrict__ rowBeg) {
  __shared__ int lrec[BINCAP];
  __shared__ int srtg[BINCAP];
  __shared__ int hist[256];
  __shared__ int off[256];       // inclusive scan; (off - hist) = exclusive
  __shared__ int cur[256];
  int t = threadIdx.x;
  int b = blockIdx.x;
  int rbase = b * BINCAP;
  int R = binCur[b] - rbase;
  if (R > BINCAP) R = BINCAP;
  if (t < 256) hist[t] = 0;
  __syncthreads();
#pragma unroll
  for (int j = 0; j < 9; ++j) {
    int idx = j * 512 + t;
    if (idx < R) {
      int r = recs[rbase + idx];
      lrec[idx] = r;
      atomicAdd(&hist[r & 255], 1);
    }
  }
  __syncthreads();
  if (t < 256) off[t] = hist[t];
  __syncthreads();
  for (int o = 1; o < 256; o <<= 1) {
    int u = 0;
    if (t < 256 && t >= o) u = off[t - o];
    __syncthreads();
    if (t < 256) off[t] += u;
    __syncthreads();
  }
  if (t < 256) {
    int ex = off[t] - hist[t];
    cur[t] = ex;
    int n = (b << 8) + t;
    if (n < N_NODES) {
      deg[n] = hist[t];
      rowBeg[n] = rbase + ex;
    }
  }
  __syncthreads();
#pragma unroll
  for (int j = 0; j < 9; ++j) {
    int idx = j * 512 + t;
    if (idx < R) {
      int r = lrec[idx];
      int slot = atomicAdd(&cur[r & 255], 1);
      srtg[slot] = r;
    }
  }
  __syncthreads();
#pragma unroll
  for (int j = 0; j < 9; ++j) {
    int idx = j * 512 + t;
    if (idx < R) {
      int r = srtg[idx];
      int node = r & 255;
      int ex = off[node] - hist[node];
      int cnt = hist[node];
      int rank = 0;
      for (int k = ex; k < ex + cnt; ++k) {
        int v = srtg[k];
        rank += (v < r) || (v == r && k < idx);
      }
      lrec[ex + rank] = r >> 8;  // src id
    }
  }
  __syncthreads();
#pragma unroll
  for (int j = 0; j < 9; ++j) {
    int idx = j * 512 + t;
    if (idx < R) recs[rbase + idx] = lrec[idx];
  }
}

// ---------------------------------------------------------------------------
// gather1 (fused combine1): h1 = relu(mean(y1l_nbrs) + b1 + y1r);
//                           z2l = fp16(h1@W2l); z2r = h1@W2r (fp32)
// 16 lanes per node, lane c owns channel c. W2 GEMM via 16-wide shuffles.
// ---------------------------------------------------------------------------
__global__ void __launch_bounds__(256) k_gather1(
    const int* __restrict__ srcSorted, const int* __restrict__ deg,
    const int* __restrict__ rowBeg, const __half* __restrict__ y1l,
    const float* __restrict__ y1r, const float* __restrict__ b1,
    const float* __restrict__ W2l, const float* __restrict__ W2r,
    __half* __restrict__ z2l, float* __restrict__ z2r) {
  int tid = blockIdx.x * 256 + threadIdx.x;
  int n = tid >> 4;
  int c = tid & 15;
  if (n >= N_NODES) return;
  int beg = rowBeg[n];
  int dg = deg[n];
  int end = beg + dg;
  float acc = 0.f;
  int i = beg;
  for (; i + 4 <= end; i += 4) {
    int s0 = srcSorted[i], s1 = srcSorted[i + 1];
    int s2 = srcSorted[i + 2], s3 = srcSorted[i + 3];
    float a0 = __half2float(y1l[(size_t)s0 * H + c]);
    float a1 = __half2float(y1l[(size_t)s1 * H + c]);
    float a2 = __half2float(y1l[(size_t)s2 * H + c]);
    float a3 = __half2float(y1l[(size_t)s3 * H + c]);
    acc += (a0 + a1) + (a2 + a3);
  }
  for (; i < end; ++i) acc += __half2float(y1l[(size_t)srcSorted[i] * H + c]);
  float inv = 1.f / fmaxf((float)dg, 1.f);
  float h1 = fmaxf(fmaf(acc, inv, b1[c] + y1r[(size_t)n * H + c]), 0.f);
  float zl = 0.f, zr = 0.f;
#pragma unroll
  for (int k = 0; k < H; ++k) {
    float hk = __shfl(h1, k, 16);
    zl = fmaf(hk, W2l[k * H + c], zl);
    zr = fmaf(hk, W2r[k * H + c], zr);
  }
  z2l[(size_t)n * H + c] = __float2half_rn(zl);
  z2r[(size_t)n * H + c] = zr;
}

// ---------------------------------------------------------------------------
// gather2 (fused combine2): h2 = fp16(mean(z2l_nbrs) + b2 + z2r)
// ---------------------------------------------------------------------------
__global__ void __launch_bounds__(256) k_gather2(
    const int* __restrict__ srcSorted, const int* __restrict__ deg,
    const int* __restrict__ rowBeg, const __half* __restrict__ z2l,
    const float* __restrict__ z2r, const float* __restrict__ b2,
    __half* __restrict__ h2) {
  int tid = blockIdx.x * 256 + threadIdx.x;
  int n = tid >> 4;
  int c = tid & 15;
  if (n >= N_NODES) return;
  int beg = rowBeg[n];
  int dg = deg[n];
  int end = beg + dg;
  float acc = 0.f;
  int i = beg;
  for (; i + 4 <= end; i += 4) {
    int s0 = srcSorted[i], s1 = srcSorted[i + 1];
    int s2 = srcSorted[i + 2], s3 = srcSorted[i + 3];
    float a0 = __half2float(z2l[(size_t)s0 * H + c]);
    float a1 = __half2float(z2l[(size_t)s1 * H + c]);
    float a2 = __half2float(z2l[(size_t)s2 * H + c]);
    float a3 = __half2float(z2l[(size_t)s3 * H + c]);
    acc += (a0 + a1) + (a2 + a3);
  }
  for (; i < end; ++i) acc += __half2float(z2l[(size_t)srcSorted[i] * H + c]);
  float inv = 1.f / fmaxf((float)dg, 1.f);
  float v = fmaf(acc, inv, b2[c] + z2r[(size_t)n * H + c]);
  h2[(size_t)n * H + c] = __float2half_rn(v);
}

// ---------------------------------------------------------------------------
// decode: out[p] = sigmoid(dot(h2[s], h2[d]))  — h2 rows are 32 B fp16
// ---------------------------------------------------------------------------
__device__ inline float dot8h(uint4 u, uint4 v) {
  float acc = 0.f;
  const unsigned int* uw = (const unsigned int*)&u;
  const unsigned int* vw = (const unsigned int*)&v;
#pragma unroll
  for (int j = 0; j < 4; ++j) {
    float2 a = __half22float2(*(const __half2*)&uw[j]);
    float2 b = __half22float2(*(const __half2*)&vw[j]);
    acc = fmaf(a.x, b.x, acc);
    acc = fmaf(a.y, b.y, acc);
  }
  return acc;
}

__global__ void __launch_bounds__(256) k_decode(
    const int* __restrict__ ps, const int* __restrict__ pd,
    const __half* __restrict__ h2, float* __restrict__ out, int P) {
  int p = blockIdx.x * 256 + threadIdx.x;
  if (p >= P) return;
  int a = ps[p];
  int b = pd[p];
  const uint4* ha = (const uint4*)(h2 + (size_t)a * H);  // 2x16B per row
  const uint4* hb = (const uint4*)(h2 + (size_t)b * H);
  uint4 u0 = ha[0], u1 = ha[1];
  uint4 v0 = hb[0], v1 = hb[1];
  float acc = dot8h(u0, v0) + dot8h(u1, v1);
  out[p] = 1.f / (1.f + __expf(-acc));
}

// ---------------------------------------------------------------------------
extern "C" void kernel_launch(void* const* d_in, const int* in_sizes, int n_in,
                              void* d_out, int out_size, void* d_ws, size_t ws_size,
                              hipStream_t stream) {
  const float* x   = (const float*)d_in[0];
  const float* W1l = (const float*)d_in[1];
  const float* b1  = (const float*)d_in[2];
  const float* W1r = (const float*)d_in[3];
  const float* W2l = (const float*)d_in[4];
  const float* b2  = (const float*)d_in[5];
  const float* W2r = (const float*)d_in[6];
  const int* ei = (const int*)d_in[7];  // [2, E] int32
  const int* di = (const int*)d_in[8];  // [2, P] int32
  const int E = in_sizes[7] / 2;
  const int P = in_sizes[8] / 2;

  const size_t NF = (size_t)N_NODES * H;
  // fp16 tables (gathered randomly; 3.2 MB each, L2-resident):
  //   y1l -> aliased as h2 after gather1 retires y1l; z2l separate.
  // fp32 per-node streams: y1r -> aliased as z2r (same thread+element).
  __half* y1l = (__half*)d_ws;          // NF halves
  __half* h2  = y1l;                    // alias (y1l dead after gather1)
  __half* z2l = y1l + NF;               // NF halves
  float*  y1r = (float*)(z2l + NF);     // NF floats
  float*  z2r = y1r;                    // alias
  int* recs   = (int*)(y1r + NF);       // NBIN * BINCAP (records -> srcSorted)
  int* binCur = recs + (size_t)NBIN * BINCAP;  // NBIN (padded to 512)
  int* deg    = binCur + 512;           // N
  int* rowBeg = deg + N_NODES;          // N

  const int lin1Blocks = ((N_NODES * 8) + 255) / 256;
  const int fillBlocks = (E + ECHUNK - 1) / ECHUNK;
  const int gatherBlocks = ((N_NODES * H) + 255) / 256;

  k_init<<<1, 512, 0, stream>>>(binCur);
  k_lin1<<<lin1Blocks, 256, 0, stream>>>(x, W1l, W1r, y1l, y1r);
  k_binfill<<<fillBlocks, 512, 0, stream>>>(ei, ei + E, binCur, recs, E);
  k_binsort<<<NBIN, 512, 0, stream>>>(recs, binCur, deg, rowBeg);
  k_gather1<<<gatherBlocks, 256, 0, stream>>>(recs, deg, rowBeg, y1l, y1r,
                                              b1, W2l, W2r, z2l, z2r);
  k_gather2<<<gatherBlocks, 256, 0, stream>>>(recs, deg, rowBeg, z2l, z2r,
                                              b2, h2);
  k_decode<<<(P + 255) / 256, 256, 0, stream>>>(di, di + P, h2, (float*)d_out, P);
}

// Round 8
// 237.359 us; speedup vs baseline: 1.1868x; 1.1868x over previous
//
#include <hip/hip_runtime.h>
#include <hip/hip_fp16.h>

#define N_NODES 100000
#define F_IN 128
#define H 16
#define NBIN 391           // ceil(N_NODES/256); bin b owns nodes [b*256, b*256+256)
#define BINCAP 4608        // per-bin record capacity (mean 4096, +8 sigma)
#define ECHUNK 4096        // edges per binfill block

// ---------------------------------------------------------------------------
// k_init: binCur[b] = b * BINCAP  (record-region cursors)
// ---------------------------------------------------------------------------
__global__ void __launch_bounds__(512) k_init(int* __restrict__ binCur) {
  int t = threadIdx.x;
  if (t < NBIN) binCur[t] = t * BINCAP;
}

// ---------------------------------------------------------------------------
// k_lin1 (v3): y1l = fp16(x @ W1l), y1r = x @ W1r (fp32).
// Split-K within the block: 256 threads = 128 nodes x 2 K-halves.
// part = readfirstlane(tid>>7) is wave-uniform -> W stays scalar-loaded
// (v1 property that v2 lost); each thread reads only its own 256 B x half
// (no v2-style 8x amplification), as 16 up-front independent float4 loads
// for MLP. Cross-part reduce via LDS [ch][node] (conflict-free), exactly 2
// fp32 addends -> commutative -> bitwise deterministic.
// ---------------------------------------------------------------------------
__global__ void __launch_bounds__(256) k_lin1(
    const float* __restrict__ x, const float* __restrict__ W1l,
    const float* __restrict__ W1r, __half* __restrict__ y1l,
    float* __restrict__ y1r) {
  __shared__ float red[2 * H * 128];   // [32 ch][128 nodes] = 16 KB
  int t = threadIdx.x;
  int part = __builtin_amdgcn_readfirstlane(t >> 7);   // 0 or 1, wave-uniform
  int ln = t & 127;
  int n = blockIdx.x * 128 + ln;
  int nc = (n < N_NODES) ? n : (N_NODES - 1);          // clamp, guard stores only
  // up-front x loads: 16 independent float4 (256 B = this thread's K-half)
  const float4* xr = (const float4*)(x + (size_t)nc * F_IN + part * (F_IN / 2));
  float4 xv[16];
#pragma unroll
  for (int j = 0; j < 16; ++j) xv[j] = xr[j];
  const float* Wl = W1l + part * (F_IN / 2) * H;       // SGPR base
  const float* Wr = W1r + part * (F_IN / 2) * H;
  float al[H], ar[H];
#pragma unroll
  for (int c = 0; c < H; ++c) { al[c] = 0.f; ar[c] = 0.f; }
#pragma unroll
  for (int j = 0; j < 16; ++j) {
    float xs[4] = {xv[j].x, xv[j].y, xv[j].z, xv[j].w};
#pragma unroll
    for (int jj = 0; jj < 4; ++jj) {
      int k = j * 4 + jj;
#pragma unroll
      for (int c = 0; c < H; ++c) {
        al[c] = fmaf(xs[jj], Wl[k * H + c], al[c]);
        ar[c] = fmaf(xs[jj], Wr[k * H + c], ar[c]);
      }
    }
  }
  // part 1 -> LDS; part 0 reduces and stores
  if (part == 1) {
#pragma unroll
    for (int c = 0; c < H; ++c) {
      red[c * 128 + ln] = al[c];
      red[(H + c) * 128 + ln] = ar[c];
    }
  }
  __syncthreads();
  if (part == 0 && n < N_NODES) {
#pragma unroll
    for (int c = 0; c < H; ++c) {
      al[c] += red[c * 128 + ln];
      ar[c] += red[(H + c) * 128 + ln];
    }
    __half2 hp[8];
#pragma unroll
    for (int q = 0; q < 8; ++q) hp[q] = __floats2half2_rn(al[2 * q], al[2 * q + 1]);
    uint4* ol = (uint4*)(y1l + (size_t)n * H);   // 32 B row = 2x uint4
    ol[0] = *(uint4*)&hp[0];
    ol[1] = *(uint4*)&hp[4];
    float4* orr = (float4*)(y1r + (size_t)n * H);
#pragma unroll
    for (int q = 0; q < 4; ++q)
      orr[q] = make_float4(ar[4 * q], ar[4 * q + 1], ar[4 * q + 2], ar[4 * q + 3]);
  }
}

// ---------------------------------------------------------------------------
// k_binfill: radix pass 1 — bin records (src<<8 | dstLow) by dst>>8.
// Per-block LDS histogram, one global cursor atomicAdd per (block,bin),
// then ranged (sequential) writes: ~2 writers per 64B line, low write amp.
// Record ORDER in a bin is nondeterministic (atomic races) but the record
// SET is deterministic; k_binsort canonicalizes the order.
// ---------------------------------------------------------------------------
__global__ void __launch_bounds__(512) k_binfill(
    const int* __restrict__ src, const int* __restrict__ dst,
    int* __restrict__ binCur, int* __restrict__ recs, int E) {
  __shared__ int hist[512];
  __shared__ int gbase[512];
  __shared__ int cnt2[512];
  int t = threadIdx.x;
  hist[t] = 0;
  cnt2[t] = 0;
  __syncthreads();
  int base = blockIdx.x * ECHUNK;
  int rec[8], bin[8];
#pragma unroll
  for (int j = 0; j < 8; ++j) {
    int e = base + j * 512 + t;
    if (e < E) {
      int s = src[e];
      int d = dst[e];
      rec[j] = (s << 8) | (d & 255);
      bin[j] = d >> 8;
      atomicAdd(&hist[bin[j]], 1);
    } else {
      bin[j] = -1;
    }
  }
  __syncthreads();
  if (t < NBIN) {
    int c = hist[t];
    gbase[t] = (c > 0) ? atomicAdd(&binCur[t], c) : 0;
  }
  __syncthreads();
#pragma unroll
  for (int j = 0; j < 8; ++j) {
    if (bin[j] >= 0) {
      int loc = atomicAdd(&cnt2[bin[j]], 1);
      int slot = gbase[bin[j]] + loc;
      if (slot < (bin[j] + 1) * BINCAP)  // safety clamp (never expected)
        recs[slot] = rec[j];
    }
  }
}

// ---------------------------------------------------------------------------
// k_binsort: radix pass 2 — one block per bin. Canonical rank-sort within
// each row makes the CSR (and thus all fp summation orders) bitwise
// deterministic run-to-run.
// ---------------------------------------------------------------------------
__global__ void __launch_bounds__(512) k_binsort(
    int* __restrict__ recs, const int* __restrict__ binCur,
    int* __restrict__ deg, int* __restrict__ rowBeg) {
  __shared__ int lrec[BINCAP];
  __shared__ int srtg[BINCAP];
  __shared__ int hist[256];
  __shared__ int off[256];       // inclusive scan; (off - hist) = exclusive
  __shared__ int cur[256];
  int t = threadIdx.x;
  int b = blockIdx.x;
  int rbase = b * BINCAP;
  int R = binCur[b] - rbase;
  if (R > BINCAP) R = BINCAP;
  if (t < 256) hist[t] = 0;
  __syncthreads();
#pragma unroll
  for (int j = 0; j < 9; ++j) {
    int idx = j * 512 + t;
    if (idx < R) {
      int r = recs[rbase + idx];
      lrec[idx] = r;
      atomicAdd(&hist[r & 255], 1);
    }
  }
  __syncthreads();
  if (t < 256) off[t] = hist[t];
  __syncthreads();
  for (int o = 1; o < 256; o <<= 1) {
    int u = 0;
    if (t < 256 && t >= o) u = off[t - o];
    __syncthreads();
    if (t < 256) off[t] += u;
    __syncthreads();
  }
  if (t < 256) {
    int ex = off[t] - hist[t];
    cur[t] = ex;
    int n = (b << 8) + t;
    if (n < N_NODES) {
      deg[n] = hist[t];
      rowBeg[n] = rbase + ex;
    }
  }
  __syncthreads();
#pragma unroll
  for (int j = 0; j < 9; ++j) {
    int idx = j * 512 + t;
    if (idx < R) {
      int r = lrec[idx];
      int slot = atomicAdd(&cur[r & 255], 1);
      srtg[slot] = r;
    }
  }
  __syncthreads();
#pragma unroll
  for (int j = 0; j < 9; ++j) {
    int idx = j * 512 + t;
    if (idx < R) {
      int r = srtg[idx];
      int node = r & 255;
      int ex = off[node] - hist[node];
      int cnt = hist[node];
      int rank = 0;
      for (int k = ex; k < ex + cnt; ++k) {
        int v = srtg[k];
        rank += (v < r) || (v == r && k < idx);
      }
      lrec[ex + rank] = r >> 8;  // src id
    }
  }
  __syncthreads();
#pragma unroll
  for (int j = 0; j < 9; ++j) {
    int idx = j * 512 + t;
    if (idx < R) recs[rbase + idx] = lrec[idx];
  }
}

// ---------------------------------------------------------------------------
// gather1 (fused combine1): h1 = relu(mean(y1l_nbrs) + b1 + y1r);
//                           z2l = fp16(h1@W2l); z2r = h1@W2r (fp32)
// 16 lanes per node, lane c owns channel c. W2 GEMM via 16-wide shuffles.
// ---------------------------------------------------------------------------
__global__ void __launch_bounds__(256) k_gather1(
    const int* __restrict__ srcSorted, const int* __restrict__ deg,
    const int* __restrict__ rowBeg, const __half* __restrict__ y1l,
    const float* __restrict__ y1r, const float* __restrict__ b1,
    const float* __restrict__ W2l, const float* __restrict__ W2r,
    __half* __restrict__ z2l, float* __restrict__ z2r) {
  int tid = blockIdx.x * 256 + threadIdx.x;
  int n = tid >> 4;
  int c = tid & 15;
  if (n >= N_NODES) return;
  int beg = rowBeg[n];
  int dg = deg[n];
  int end = beg + dg;
  float acc = 0.f;
  int i = beg;
  for (; i + 4 <= end; i += 4) {
    int s0 = srcSorted[i], s1 = srcSorted[i + 1];
    int s2 = srcSorted[i + 2], s3 = srcSorted[i + 3];
    float a0 = __half2float(y1l[(size_t)s0 * H + c]);
    float a1 = __half2float(y1l[(size_t)s1 * H + c]);
    float a2 = __half2float(y1l[(size_t)s2 * H + c]);
    float a3 = __half2float(y1l[(size_t)s3 * H + c]);
    acc += (a0 + a1) + (a2 + a3);
  }
  for (; i < end; ++i) acc += __half2float(y1l[(size_t)srcSorted[i] * H + c]);
  float inv = 1.f / fmaxf((float)dg, 1.f);
  float h1 = fmaxf(fmaf(acc, inv, b1[c] + y1r[(size_t)n * H + c]), 0.f);
  float zl = 0.f, zr = 0.f;
#pragma unroll
  for (int k = 0; k < H; ++k) {
    float hk = __shfl(h1, k, 16);
    zl = fmaf(hk, W2l[k * H + c], zl);
    zr = fmaf(hk, W2r[k * H + c], zr);
  }
  z2l[(size_t)n * H + c] = __float2half_rn(zl);
  z2r[(size_t)n * H + c] = zr;
}

// ---------------------------------------------------------------------------
// gather2 (fused combine2): h2 = fp16(mean(z2l_nbrs) + b2 + z2r)
// ---------------------------------------------------------------------------
__global__ void __launch_bounds__(256) k_gather2(
    const int* __restrict__ srcSorted, const int* __restrict__ deg,
    const int* __restrict__ rowBeg, const __half* __restrict__ z2l,
    const float* __restrict__ z2r, const float* __restrict__ b2,
    __half* __restrict__ h2) {
  int tid = blockIdx.x * 256 + threadIdx.x;
  int n = tid >> 4;
  int c = tid & 15;
  if (n >= N_NODES) return;
  int beg = rowBeg[n];
  int dg = deg[n];
  int end = beg + dg;
  float acc = 0.f;
  int i = beg;
  for (; i + 4 <= end; i += 4) {
    int s0 = srcSorted[i], s1 = srcSorted[i + 1];
    int s2 = srcSorted[i + 2], s3 = srcSorted[i + 3];
    float a0 = __half2float(z2l[(size_t)s0 * H + c]);
    float a1 = __half2float(z2l[(size_t)s1 * H + c]);
    float a2 = __half2float(z2l[(size_t)s2 * H + c]);
    float a3 = __half2float(z2l[(size_t)s3 * H + c]);
    acc += (a0 + a1) + (a2 + a3);
  }
  for (; i < end; ++i) acc += __half2float(z2l[(size_t)srcSorted[i] * H + c]);
  float inv = 1.f / fmaxf((float)dg, 1.f);
  float v = fmaf(acc, inv, b2[c] + z2r[(size_t)n * H + c]);
  h2[(size_t)n * H + c] = __float2half_rn(v);
}

// ---------------------------------------------------------------------------
// decode: out[p] = sigmoid(dot(h2[s], h2[d]))  — h2 rows are 32 B fp16
// ---------------------------------------------------------------------------
__device__ inline float dot8h(uint4 u, uint4 v) {
  float acc = 0.f;
  const unsigned int* uw = (const unsigned int*)&u;
  const unsigned int* vw = (const unsigned int*)&v;
#pragma unroll
  for (int j = 0; j < 4; ++j) {
    float2 a = __half22float2(*(const __half2*)&uw[j]);
    float2 b = __half22float2(*(const __half2*)&vw[j]);
    acc = fmaf(a.x, b.x, acc);
    acc = fmaf(a.y, b.y, acc);
  }
  return acc;
}

__global__ void __launch_bounds__(256) k_decode(
    const int* __restrict__ ps, const int* __restrict__ pd,
    const __half* __restrict__ h2, float* __restrict__ out, int P) {
  int p = blockIdx.x * 256 + threadIdx.x;
  if (p >= P) return;
  int a = ps[p];
  int b = pd[p];
  const uint4* ha = (const uint4*)(h2 + (size_t)a * H);  // 2x16B per row
  const uint4* hb = (const uint4*)(h2 + (size_t)b * H);
  uint4 u0 = ha[0], u1 = ha[1];
  uint4 v0 = hb[0], v1 = hb[1];
  float acc = dot8h(u0, v0) + dot8h(u1, v1);
  out[p] = 1.f / (1.f + __expf(-acc));
}

// ---------------------------------------------------------------------------
extern "C" void kernel_launch(void* const* d_in, const int* in_sizes, int n_in,
                              void* d_out, int out_size, void* d_ws, size_t ws_size,
                              hipStream_t stream) {
  const float* x   = (const float*)d_in[0];
  const float* W1l = (const float*)d_in[1];
  const float* b1  = (const float*)d_in[2];
  const float* W1r = (const float*)d_in[3];
  const float* W2l = (const float*)d_in[4];
  const float* b2  = (const float*)d_in[5];
  const float* W2r = (const float*)d_in[6];
  const int* ei = (const int*)d_in[7];  // [2, E] int32
  const int* di = (const int*)d_in[8];  // [2, P] int32
  const int E = in_sizes[7] / 2;
  const int P = in_sizes[8] / 2;

  const size_t NF = (size_t)N_NODES * H;
  // fp16 tables (gathered randomly; 3.2 MB each, L2-resident):
  //   y1l -> aliased as h2 after gather1 retires y1l; z2l separate.
  // fp32 per-node streams: y1r -> aliased as z2r (same thread+element).
  __half* y1l = (__half*)d_ws;          // NF halves
  __half* h2  = y1l;                    // alias (y1l dead after gather1)
  __half* z2l = y1l + NF;               // NF halves
  float*  y1r = (float*)(z2l + NF);     // NF floats
  float*  z2r = y1r;                    // alias
  int* recs   = (int*)(y1r + NF);       // NBIN * BINCAP (records -> srcSorted)
  int* binCur = recs + (size_t)NBIN * BINCAP;  // NBIN (padded to 512)
  int* deg    = binCur + 512;           // N
  int* rowBeg = deg + N_NODES;          // N

  const int lin1Blocks = (N_NODES + 127) / 128;   // 128 nodes per 256-thr block
  const int fillBlocks = (E + ECHUNK - 1) / ECHUNK;
  const int gatherBlocks = ((N_NODES * H) + 255) / 256;

  k_init<<<1, 512, 0, stream>>>(binCur);
  k_lin1<<<lin1Blocks, 256, 0, stream>>>(x, W1l, W1r, y1l, y1r);
  k_binfill<<<fillBlocks, 512, 0, stream>>>(ei, ei + E, binCur, recs, E);
  k_binsort<<<NBIN, 512, 0, stream>>>(recs, binCur, deg, rowBeg);
  k_gather1<<<gatherBlocks, 256, 0, stream>>>(recs, deg, rowBeg, y1l, y1r,
                                              b1, W2l, W2r, z2l, z2r);
  k_gather2<<<gatherBlocks, 256, 0, stream>>>(recs, deg, rowBeg, z2l, z2r,
                                              b2, h2);
  k_decode<<<(P + 255) / 256, 256, 0, stream>>>(di, di + P, h2, (float*)d_out, P);
}

// Round 9
// 226.193 us; speedup vs baseline: 1.2453x; 1.0494x over previous
//
#include <hip/hip_runtime.h>
#include <hip/hip_fp16.h>

#define N_NODES 100000
#define F_IN 128
#define H 16
#define NBIN 391           // ceil(N_NODES/256); bin b owns nodes [b*256, b*256+256)
#define BINCAP 4608        // per-bin record capacity (mean 4096, +8 sigma)
#define ECHUNK 4096        // edges per binfill block

// ---------------------------------------------------------------------------
// k_init: binCur[b] = b * BINCAP  (record-region cursors)
// ---------------------------------------------------------------------------
__global__ void __launch_bounds__(512) k_init(int* __restrict__ binCur) {
  int t = threadIdx.x;
  if (t < NBIN) binCur[t] = t * BINCAP;
}

// ---------------------------------------------------------------------------
// k_lin1 (v3): y1l = fp16(x @ W1l), y1r = x @ W1r (fp32).
// Split-K within the block: 256 threads = 128 nodes x 2 K-halves.
// part = readfirstlane(tid>>7) is wave-uniform -> W stays scalar-loaded;
// 16 up-front independent float4 x loads for MLP. Cross-part reduce via LDS,
// exactly 2 fp32 addends -> commutative -> bitwise deterministic.
// ---------------------------------------------------------------------------
__global__ void __launch_bounds__(256) k_lin1(
    const float* __restrict__ x, const float* __restrict__ W1l,
    const float* __restrict__ W1r, __half* __restrict__ y1l,
    float* __restrict__ y1r) {
  __shared__ float red[2 * H * 128];   // [32 ch][128 nodes] = 16 KB
  int t = threadIdx.x;
  int part = __builtin_amdgcn_readfirstlane(t >> 7);   // 0 or 1, wave-uniform
  int ln = t & 127;
  int n = blockIdx.x * 128 + ln;
  int nc = (n < N_NODES) ? n : (N_NODES - 1);          // clamp, guard stores only
  const float4* xr = (const float4*)(x + (size_t)nc * F_IN + part * (F_IN / 2));
  float4 xv[16];
#pragma unroll
  for (int j = 0; j < 16; ++j) xv[j] = xr[j];
  const float* Wl = W1l + part * (F_IN / 2) * H;       // SGPR base
  const float* Wr = W1r + part * (F_IN / 2) * H;
  float al[H], ar[H];
#pragma unroll
  for (int c = 0; c < H; ++c) { al[c] = 0.f; ar[c] = 0.f; }
#pragma unroll
  for (int j = 0; j < 16; ++j) {
    float xs[4] = {xv[j].x, xv[j].y, xv[j].z, xv[j].w};
#pragma unroll
    for (int jj = 0; jj < 4; ++jj) {
      int k = j * 4 + jj;
#pragma unroll
      for (int c = 0; c < H; ++c) {
        al[c] = fmaf(xs[jj], Wl[k * H + c], al[c]);
        ar[c] = fmaf(xs[jj], Wr[k * H + c], ar[c]);
      }
    }
  }
  if (part == 1) {
#pragma unroll
    for (int c = 0; c < H; ++c) {
      red[c * 128 + ln] = al[c];
      red[(H + c) * 128 + ln] = ar[c];
    }
  }
  __syncthreads();
  if (part == 0 && n < N_NODES) {
#pragma unroll
    for (int c = 0; c < H; ++c) {
      al[c] += red[c * 128 + ln];
      ar[c] += red[(H + c) * 128 + ln];
    }
    __half2 hp[8];
#pragma unroll
    for (int q = 0; q < 8; ++q) hp[q] = __floats2half2_rn(al[2 * q], al[2 * q + 1]);
    uint4* ol = (uint4*)(y1l + (size_t)n * H);   // 32 B row = 2x uint4
    ol[0] = *(uint4*)&hp[0];
    ol[1] = *(uint4*)&hp[4];
    float4* orr = (float4*)(y1r + (size_t)n * H);
#pragma unroll
    for (int q = 0; q < 4; ++q)
      orr[q] = make_float4(ar[4 * q], ar[4 * q + 1], ar[4 * q + 2], ar[4 * q + 3]);
  }
}

// ---------------------------------------------------------------------------
// k_binfill: radix pass 1 — bin records (src<<8 | dstLow) by dst>>8.
// ---------------------------------------------------------------------------
__global__ void __launch_bounds__(512) k_binfill(
    const int* __restrict__ src, const int* __restrict__ dst,
    int* __restrict__ binCur, int* __restrict__ recs, int E) {
  __shared__ int hist[512];
  __shared__ int gbase[512];
  __shared__ int cnt2[512];
  int t = threadIdx.x;
  hist[t] = 0;
  cnt2[t] = 0;
  __syncthreads();
  int base = blockIdx.x * ECHUNK;
  int rec[8], bin[8];
#pragma unroll
  for (int j = 0; j < 8; ++j) {
    int e = base + j * 512 + t;
    if (e < E) {
      int s = src[e];
      int d = dst[e];
      rec[j] = (s << 8) | (d & 255);
      bin[j] = d >> 8;
      atomicAdd(&hist[bin[j]], 1);
    } else {
      bin[j] = -1;
    }
  }
  __syncthreads();
  if (t < NBIN) {
    int c = hist[t];
    gbase[t] = (c > 0) ? atomicAdd(&binCur[t], c) : 0;
  }
  __syncthreads();
#pragma unroll
  for (int j = 0; j < 8; ++j) {
    if (bin[j] >= 0) {
      int loc = atomicAdd(&cnt2[bin[j]], 1);
      int slot = gbase[bin[j]] + loc;
      if (slot < (bin[j] + 1) * BINCAP)  // safety clamp (never expected)
        recs[slot] = rec[j];
    }
  }
}

// ---------------------------------------------------------------------------
// k_binsort: radix pass 2 — one block per bin. Canonical rank-sort within
// each row makes the CSR (and thus all fp summation orders) bitwise
// deterministic run-to-run.
// ---------------------------------------------------------------------------
__global__ void __launch_bounds__(512) k_binsort(
    int* __restrict__ recs, const int* __restrict__ binCur,
    int* __restrict__ deg, int* __restrict__ rowBeg) {
  __shared__ int lrec[BINCAP];
  __shared__ int srtg[BINCAP];
  __shared__ int hist[256];
  __shared__ int off[256];       // inclusive scan; (off - hist) = exclusive
  __shared__ int cur[256];
  int t = threadIdx.x;
  int b = blockIdx.x;
  int rbase = b * BINCAP;
  int R = binCur[b] - rbase;
  if (R > BINCAP) R = BINCAP;
  if (t < 256) hist[t] = 0;
  __syncthreads();
#pragma unroll
  for (int j = 0; j < 9; ++j) {
    int idx = j * 512 + t;
    if (idx < R) {
      int r = recs[rbase + idx];
      lrec[idx] = r;
      atomicAdd(&hist[r & 255], 1);
    }
  }
  __syncthreads();
  if (t < 256) off[t] = hist[t];
  __syncthreads();
  for (int o = 1; o < 256; o <<= 1) {
    int u = 0;
    if (t < 256 && t >= o) u = off[t - o];
    __syncthreads();
    if (t < 256) off[t] += u;
    __syncthreads();
  }
  if (t < 256) {
    int ex = off[t] - hist[t];
    cur[t] = ex;
    int n = (b << 8) + t;
    if (n < N_NODES) {
      deg[n] = hist[t];
      rowBeg[n] = rbase + ex;
    }
  }
  __syncthreads();
#pragma unroll
  for (int j = 0; j < 9; ++j) {
    int idx = j * 512 + t;
    if (idx < R) {
      int r = lrec[idx];
      int slot = atomicAdd(&cur[r & 255], 1);
      srtg[slot] = r;
    }
  }
  __syncthreads();
#pragma unroll
  for (int j = 0; j < 9; ++j) {
    int idx = j * 512 + t;
    if (idx < R) {
      int r = srtg[idx];
      int node = r & 255;
      int ex = off[node] - hist[node];
      int cnt = hist[node];
      int rank = 0;
      for (int k = ex; k < ex + cnt; ++k) {
        int v = srtg[k];
        rank += (v < r) || (v == r && k < idx);
      }
      lrec[ex + rank] = r >> 8;  // src id
    }
  }
  __syncthreads();
#pragma unroll
  for (int j = 0; j < 9; ++j) {
    int idx = j * 512 + t;
    if (idx < R) recs[rbase + idx] = lrec[idx];
  }
}

// ---------------------------------------------------------------------------
// gather1 (v2, 4 lanes/node): lane q owns channels 4q..4q+3.
// Per neighbor: one uint2 (8 B = 4 halves) data load; indices lane-split
// and redistributed via width-4 shuffles (coalesced, 4x fewer loads).
// Epilogue: h1 = relu(mean + b1 + y1r); W2 matvec via width-4 shuffle
// transpose; z2l = fp16, z2r = fp32.
// ---------------------------------------------------------------------------
__global__ void __launch_bounds__(256) k_gather1(
    const int* __restrict__ srcSorted, const int* __restrict__ deg,
    const int* __restrict__ rowBeg, const __half* __restrict__ y1l,
    const float* __restrict__ y1r, const float* __restrict__ b1,
    const float* __restrict__ W2l, const float* __restrict__ W2r,
    __half* __restrict__ z2l, float* __restrict__ z2r) {
  int tid = blockIdx.x * 256 + threadIdx.x;
  int n = tid >> 2;
  int q = tid & 3;
  if (n >= N_NODES) return;
  int beg = rowBeg[n];
  int dg = deg[n];
  int end = beg + dg;
  float acc0 = 0.f, acc1 = 0.f, acc2 = 0.f, acc3 = 0.f;
  int i = beg;
  for (; i + 4 <= end; i += 4) {
    int sq = srcSorted[i + q];          // coalesced: lane q takes index i+q
#pragma unroll
    for (int j = 0; j < 4; ++j) {
      int sj = __shfl(sq, j, 4);
      uint2 v = *(const uint2*)(y1l + (size_t)sj * H + q * 4);
      float2 p0 = __half22float2(*(const __half2*)&v.x);
      float2 p1 = __half22float2(*(const __half2*)&v.y);
      acc0 += p0.x; acc1 += p0.y; acc2 += p1.x; acc3 += p1.y;
    }
  }
  for (; i < end; ++i) {
    int sj = srcSorted[i];
    uint2 v = *(const uint2*)(y1l + (size_t)sj * H + q * 4);
    float2 p0 = __half22float2(*(const __half2*)&v.x);
    float2 p1 = __half22float2(*(const __half2*)&v.y);
    acc0 += p0.x; acc1 += p0.y; acc2 += p1.x; acc3 += p1.y;
  }
  float inv = 1.f / fmaxf((float)dg, 1.f);
  float4 yr = *(const float4*)(y1r + (size_t)n * H + q * 4);
  float4 bb = *(const float4*)(b1 + q * 4);
  float h1x = fmaxf(fmaf(acc0, inv, bb.x + yr.x), 0.f);
  float h1y = fmaxf(fmaf(acc1, inv, bb.y + yr.y), 0.f);
  float h1z = fmaxf(fmaf(acc2, inv, bb.z + yr.z), 0.f);
  float h1w = fmaxf(fmaf(acc3, inv, bb.w + yr.w), 0.f);
  float zl0 = 0.f, zl1 = 0.f, zl2 = 0.f, zl3 = 0.f;
  float zr0 = 0.f, zr1 = 0.f, zr2 = 0.f, zr3 = 0.f;
#pragma unroll
  for (int sl = 0; sl < 4; ++sl) {
    float hx = __shfl(h1x, sl, 4);
    float hy = __shfl(h1y, sl, 4);
    float hz = __shfl(h1z, sl, 4);
    float hw = __shfl(h1w, sl, 4);
    float hk4[4] = {hx, hy, hz, hw};
#pragma unroll
    for (int j = 0; j < 4; ++j) {
      int k = sl * 4 + j;               // h1 channel index
      float4 wl = *(const float4*)(W2l + k * H + q * 4);
      float4 wr = *(const float4*)(W2r + k * H + q * 4);
      float hk = hk4[j];
      zl0 = fmaf(hk, wl.x, zl0); zl1 = fmaf(hk, wl.y, zl1);
      zl2 = fmaf(hk, wl.z, zl2); zl3 = fmaf(hk, wl.w, zl3);
      zr0 = fmaf(hk, wr.x, zr0); zr1 = fmaf(hk, wr.y, zr1);
      zr2 = fmaf(hk, wr.z, zr2); zr3 = fmaf(hk, wr.w, zr3);
    }
  }
  __half2 hl0 = __floats2half2_rn(zl0, zl1);
  __half2 hl1 = __floats2half2_rn(zl2, zl3);
  uint2 pk;
  pk.x = *(unsigned int*)&hl0;
  pk.y = *(unsigned int*)&hl1;
  *(uint2*)(z2l + (size_t)n * H + q * 4) = pk;
  *(float4*)(z2r + (size_t)n * H + q * 4) = make_float4(zr0, zr1, zr2, zr3);
}

// ---------------------------------------------------------------------------
// gather2 (v2, 4 lanes/node): h2 = fp16(mean(z2l_nbrs) + b2 + z2r)
// ---------------------------------------------------------------------------
__global__ void __launch_bounds__(256) k_gather2(
    const int* __restrict__ srcSorted, const int* __restrict__ deg,
    const int* __restrict__ rowBeg, const __half* __restrict__ z2l,
    const float* __restrict__ z2r, const float* __restrict__ b2,
    __half* __restrict__ h2) {
  int tid = blockIdx.x * 256 + threadIdx.x;
  int n = tid >> 2;
  int q = tid & 3;
  if (n >= N_NODES) return;
  int beg = rowBeg[n];
  int dg = deg[n];
  int end = beg + dg;
  float acc0 = 0.f, acc1 = 0.f, acc2 = 0.f, acc3 = 0.f;
  int i = beg;
  for (; i + 4 <= end; i += 4) {
    int sq = srcSorted[i + q];
#pragma unroll
    for (int j = 0; j < 4; ++j) {
      int sj = __shfl(sq, j, 4);
      uint2 v = *(const uint2*)(z2l + (size_t)sj * H + q * 4);
      float2 p0 = __half22float2(*(const __half2*)&v.x);
      float2 p1 = __half22float2(*(const __half2*)&v.y);
      acc0 += p0.x; acc1 += p0.y; acc2 += p1.x; acc3 += p1.y;
    }
  }
  for (; i < end; ++i) {
    int sj = srcSorted[i];
    uint2 v = *(const uint2*)(z2l + (size_t)sj * H + q * 4);
    float2 p0 = __half22float2(*(const __half2*)&v.x);
    float2 p1 = __half22float2(*(const __half2*)&v.y);
    acc0 += p0.x; acc1 += p0.y; acc2 += p1.x; acc3 += p1.y;
  }
  float inv = 1.f / fmaxf((float)dg, 1.f);
  float4 zr = *(const float4*)(z2r + (size_t)n * H + q * 4);
  float4 bb = *(const float4*)(b2 + q * 4);
  float v0 = fmaf(acc0, inv, bb.x + zr.x);
  float v1 = fmaf(acc1, inv, bb.y + zr.y);
  float v2 = fmaf(acc2, inv, bb.z + zr.z);
  float v3 = fmaf(acc3, inv, bb.w + zr.w);
  __half2 h0 = __floats2half2_rn(v0, v1);
  __half2 h1 = __floats2half2_rn(v2, v3);
  uint2 pk;
  pk.x = *(unsigned int*)&h0;
  pk.y = *(unsigned int*)&h1;
  *(uint2*)(h2 + (size_t)n * H + q * 4) = pk;
}

// ---------------------------------------------------------------------------
// decode: out[p] = sigmoid(dot(h2[s], h2[d]))  — h2 rows are 32 B fp16
// ---------------------------------------------------------------------------
__device__ inline float dot8h(uint4 u, uint4 v) {
  float acc = 0.f;
  const unsigned int* uw = (const unsigned int*)&u;
  const unsigned int* vw = (const unsigned int*)&v;
#pragma unroll
  for (int j = 0; j < 4; ++j) {
    float2 a = __half22float2(*(const __half2*)&uw[j]);
    float2 b = __half22float2(*(const __half2*)&vw[j]);
    acc = fmaf(a.x, b.x, acc);
    acc = fmaf(a.y, b.y, acc);
  }
  return acc;
}

__global__ void __launch_bounds__(256) k_decode(
    const int* __restrict__ ps, const int* __restrict__ pd,
    const __half* __restrict__ h2, float* __restrict__ out, int P) {
  int p = blockIdx.x * 256 + threadIdx.x;
  if (p >= P) return;
  int a = ps[p];
  int b = pd[p];
  const uint4* ha = (const uint4*)(h2 + (size_t)a * H);  // 2x16B per row
  const uint4* hb = (const uint4*)(h2 + (size_t)b * H);
  uint4 u0 = ha[0], u1 = ha[1];
  uint4 v0 = hb[0], v1 = hb[1];
  float acc = dot8h(u0, v0) + dot8h(u1, v1);
  out[p] = 1.f / (1.f + __expf(-acc));
}

// ---------------------------------------------------------------------------
extern "C" void kernel_launch(void* const* d_in, const int* in_sizes, int n_in,
                              void* d_out, int out_size, void* d_ws, size_t ws_size,
                              hipStream_t stream) {
  const float* x   = (const float*)d_in[0];
  const float* W1l = (const float*)d_in[1];
  const float* b1  = (const float*)d_in[2];
  const float* W1r = (const float*)d_in[3];
  const float* W2l = (const float*)d_in[4];
  const float* b2  = (const float*)d_in[5];
  const float* W2r = (const float*)d_in[6];
  const int* ei = (const int*)d_in[7];  // [2, E] int32
  const int* di = (const int*)d_in[8];  // [2, P] int32
  const int E = in_sizes[7] / 2;
  const int P = in_sizes[8] / 2;

  const size_t NF = (size_t)N_NODES * H;
  // fp16 tables (gathered randomly; 3.2 MB each, L2-resident):
  //   y1l -> aliased as h2 after gather1 retires y1l; z2l separate.
  // fp32 per-node streams: y1r -> aliased as z2r (same thread+element).
  __half* y1l = (__half*)d_ws;          // NF halves
  __half* h2  = y1l;                    // alias (y1l dead after gather1)
  __half* z2l = y1l + NF;               // NF halves
  float*  y1r = (float*)(z2l + NF);     // NF floats
  float*  z2r = y1r;                    // alias
  int* recs   = (int*)(y1r + NF);       // NBIN * BINCAP (records -> srcSorted)
  int* binCur = recs + (size_t)NBIN * BINCAP;  // NBIN (padded to 512)
  int* deg    = binCur + 512;           // N
  int* rowBeg = deg + N_NODES;          // N

  const int lin1Blocks = (N_NODES + 127) / 128;   // 128 nodes per 256-thr block
  const int fillBlocks = (E + ECHUNK - 1) / ECHUNK;
  const int gatherBlocks = ((N_NODES * 4) + 255) / 256;   // 4 lanes/node

  k_init<<<1, 512, 0, stream>>>(binCur);
  k_lin1<<<lin1Blocks, 256, 0, stream>>>(x, W1l, W1r, y1l, y1r);
  k_binfill<<<fillBlocks, 512, 0, stream>>>(ei, ei + E, binCur, recs, E);
  k_binsort<<<NBIN, 512, 0, stream>>>(recs, binCur, deg, rowBeg);
  k_gather1<<<gatherBlocks, 256, 0, stream>>>(recs, deg, rowBeg, y1l, y1r,
                                              b1, W2l, W2r, z2l, z2r);
  k_gather2<<<gatherBlocks, 256, 0, stream>>>(recs, deg, rowBeg, z2l, z2r,
                                              b2, h2);
  k_decode<<<(P + 255) / 256, 256, 0, stream>>>(di, di + P, h2, (float*)d_out, P);
}

// Round 10
// 225.434 us; speedup vs baseline: 1.2495x; 1.0034x over previous
//
#include <hip/hip_runtime.h>
#include <hip/hip_fp16.h>

#define N_NODES 100000
#define F_IN 128
#define H 16
#define NBIN 391           // ceil(N_NODES/256); bin b owns nodes [b*256, b*256+256)
#define BINCAP 4608        // per-bin record capacity (mean 4096, +8 sigma)
#define ECHUNK 4096        // edges per binfill block
#define QSCALE 4096.0f     // int16 fixed-point scale (range ±8, err 1.2e-4)
#define QINV (1.0f / 4096.0f)

// Pack two floats to int16 fixed-point (round-nearest, clamped)
__device__ inline unsigned int packi16(float a, float b) {
  int ia = __float2int_rn(fminf(fmaxf(a * QSCALE, -32767.f), 32767.f));
  int ib = __float2int_rn(fminf(fmaxf(b * QSCALE, -32767.f), 32767.f));
  return (unsigned int)((ia & 0xffff) | (ib << 16));
}

// ---------------------------------------------------------------------------
// k_init: binCur[b] = b * BINCAP  (record-region cursors)
// ---------------------------------------------------------------------------
__global__ void __launch_bounds__(512) k_init(int* __restrict__ binCur) {
  int t = threadIdx.x;
  if (t < NBIN) binCur[t] = t * BINCAP;
}

// ---------------------------------------------------------------------------
// k_lin1 (v3): y1l = i16fx(x @ W1l), y1r = x @ W1r (fp32).
// Split-K within the block: 256 threads = 128 nodes x 2 K-halves.
// part = readfirstlane(tid>>7) is wave-uniform -> W stays scalar-loaded;
// 16 up-front independent float4 x loads for MLP. Cross-part reduce via LDS,
// exactly 2 fp32 addends -> commutative -> bitwise deterministic.
// ---------------------------------------------------------------------------
__global__ void __launch_bounds__(256) k_lin1(
    const float* __restrict__ x, const float* __restrict__ W1l,
    const float* __restrict__ W1r, unsigned short* __restrict__ y1l,
    float* __restrict__ y1r) {
  __shared__ float red[2 * H * 128];   // [32 ch][128 nodes] = 16 KB
  int t = threadIdx.x;
  int part = __builtin_amdgcn_readfirstlane(t >> 7);   // 0 or 1, wave-uniform
  int ln = t & 127;
  int n = blockIdx.x * 128 + ln;
  int nc = (n < N_NODES) ? n : (N_NODES - 1);          // clamp, guard stores only
  const float4* xr = (const float4*)(x + (size_t)nc * F_IN + part * (F_IN / 2));
  float4 xv[16];
#pragma unroll
  for (int j = 0; j < 16; ++j) xv[j] = xr[j];
  const float* Wl = W1l + part * (F_IN / 2) * H;       // SGPR base
  const float* Wr = W1r + part * (F_IN / 2) * H;
  float al[H], ar[H];
#pragma unroll
  for (int c = 0; c < H; ++c) { al[c] = 0.f; ar[c] = 0.f; }
#pragma unroll
  for (int j = 0; j < 16; ++j) {
    float xs[4] = {xv[j].x, xv[j].y, xv[j].z, xv[j].w};
#pragma unroll
    for (int jj = 0; jj < 4; ++jj) {
      int k = j * 4 + jj;
#pragma unroll
      for (int c = 0; c < H; ++c) {
        al[c] = fmaf(xs[jj], Wl[k * H + c], al[c]);
        ar[c] = fmaf(xs[jj], Wr[k * H + c], ar[c]);
      }
    }
  }
  if (part == 1) {
#pragma unroll
    for (int c = 0; c < H; ++c) {
      red[c * 128 + ln] = al[c];
      red[(H + c) * 128 + ln] = ar[c];
    }
  }
  __syncthreads();
  if (part == 0 && n < N_NODES) {
#pragma unroll
    for (int c = 0; c < H; ++c) {
      al[c] += red[c * 128 + ln];
      ar[c] += red[(H + c) * 128 + ln];
    }
    uint4 w0, w1;
    w0.x = packi16(al[0], al[1]);  w0.y = packi16(al[2], al[3]);
    w0.z = packi16(al[4], al[5]);  w0.w = packi16(al[6], al[7]);
    w1.x = packi16(al[8], al[9]);  w1.y = packi16(al[10], al[11]);
    w1.z = packi16(al[12], al[13]); w1.w = packi16(al[14], al[15]);
    uint4* ol = (uint4*)(y1l + (size_t)n * H);   // 32 B row
    ol[0] = w0;
    ol[1] = w1;
    float4* orr = (float4*)(y1r + (size_t)n * H);
#pragma unroll
    for (int q = 0; q < 4; ++q)
      orr[q] = make_float4(ar[4 * q], ar[4 * q + 1], ar[4 * q + 2], ar[4 * q + 3]);
  }
}

// ---------------------------------------------------------------------------
// k_binfill: radix pass 1 — bin records (src<<8 | dstLow) by dst>>8.
// Record ORDER is nondeterministic; record SET is deterministic. Downstream
// integer accumulation makes order irrelevant.
// ---------------------------------------------------------------------------
__global__ void __launch_bounds__(512) k_binfill(
    const int* __restrict__ src, const int* __restrict__ dst,
    int* __restrict__ binCur, int* __restrict__ recs, int E) {
  __shared__ int hist[512];
  __shared__ int gbase[512];
  __shared__ int cnt2[512];
  int t = threadIdx.x;
  hist[t] = 0;
  cnt2[t] = 0;
  __syncthreads();
  int base = blockIdx.x * ECHUNK;
  int rec[8], bin[8];
#pragma unroll
  for (int j = 0; j < 8; ++j) {
    int e = base + j * 512 + t;
    if (e < E) {
      int s = src[e];
      int d = dst[e];
      rec[j] = (s << 8) | (d & 255);
      bin[j] = d >> 8;
      atomicAdd(&hist[bin[j]], 1);
    } else {
      bin[j] = -1;
    }
  }
  __syncthreads();
  if (t < NBIN) {
    int c = hist[t];
    gbase[t] = (c > 0) ? atomicAdd(&binCur[t], c) : 0;
  }
  __syncthreads();
#pragma unroll
  for (int j = 0; j < 8; ++j) {
    if (bin[j] >= 0) {
      int loc = atomicAdd(&cnt2[bin[j]], 1);
      int slot = gbase[bin[j]] + loc;
      if (slot < (bin[j] + 1) * BINCAP)  // safety clamp (never expected)
        recs[slot] = rec[j];
    }
  }
}

// ---------------------------------------------------------------------------
// k_group (replaces k_binsort): one block per bin. Load records to LDS,
// histogram dstLow, scan -> deg/rowBeg, then scatter src ids DIRECTLY to
// final global CSR slots (recs region is dead after the load phase; writes
// span one 18 KB L2-local region). Row-internal order is nondeterministic,
// which is fine: downstream accumulation is integer (order-invariant).
// ---------------------------------------------------------------------------
__global__ void __launch_bounds__(512) k_group(
    int* __restrict__ recs, const int* __restrict__ binCur,
    int* __restrict__ deg, int* __restrict__ rowBeg) {
  __shared__ int lrec[BINCAP];
  __shared__ int hist[256];
  __shared__ int off[256];       // inclusive scan; (off - hist) = exclusive
  __shared__ int cur[256];
  int t = threadIdx.x;
  int b = blockIdx.x;
  int rbase = b * BINCAP;
  int R = binCur[b] - rbase;
  if (R > BINCAP) R = BINCAP;
  if (t < 256) hist[t] = 0;
  __syncthreads();
#pragma unroll
  for (int j = 0; j < 9; ++j) {
    int idx = j * 512 + t;
    if (idx < R) {
      int r = recs[rbase + idx];
      lrec[idx] = r;
      atomicAdd(&hist[r & 255], 1);
    }
  }
  __syncthreads();
  if (t < 256) off[t] = hist[t];
  __syncthreads();
  for (int o = 1; o < 256; o <<= 1) {
    int u = 0;
    if (t < 256 && t >= o) u = off[t - o];
    __syncthreads();
    if (t < 256) off[t] += u;
    __syncthreads();
  }
  if (t < 256) {
    int ex = off[t] - hist[t];
    cur[t] = ex;
    int n = (b << 8) + t;
    if (n < N_NODES) {
      deg[n] = hist[t];
      rowBeg[n] = rbase + ex;
    }
  }
  __syncthreads();
#pragma unroll
  for (int j = 0; j < 9; ++j) {
    int idx = j * 512 + t;
    if (idx < R) {
      int r = lrec[idx];
      int slot = atomicAdd(&cur[r & 255], 1);
      recs[rbase + slot] = r >> 8;   // direct final write (L2-local region)
    }
  }
}

// ---------------------------------------------------------------------------
// gather1 (4 lanes/node): lane q owns channels 4q..4q+3. Per neighbor one
// uint2 (4 int16) load; int32 accumulation (exact, order-invariant).
// Epilogue: h1 = relu(mean + b1 + y1r); W2 matvec via width-4 shuffle
// transpose; z2l = i16fx, z2r = fp32.
// ---------------------------------------------------------------------------
__global__ void __launch_bounds__(256) k_gather1(
    const int* __restrict__ srcSorted, const int* __restrict__ deg,
    const int* __restrict__ rowBeg, const unsigned short* __restrict__ y1l,
    const float* __restrict__ y1r, const float* __restrict__ b1,
    const float* __restrict__ W2l, const float* __restrict__ W2r,
    unsigned short* __restrict__ z2l, float* __restrict__ z2r) {
  int tid = blockIdx.x * 256 + threadIdx.x;
  int n = tid >> 2;
  int q = tid & 3;
  if (n >= N_NODES) return;
  int beg = rowBeg[n];
  int dg = deg[n];
  int end = beg + dg;
  int acc0 = 0, acc1 = 0, acc2 = 0, acc3 = 0;
  int i = beg;
  for (; i + 4 <= end; i += 4) {
    int sq = srcSorted[i + q];          // coalesced: lane q takes index i+q
#pragma unroll
    for (int j = 0; j < 4; ++j) {
      int sj = __shfl(sq, j, 4);
      uint2 v = *(const uint2*)(y1l + (size_t)sj * H + q * 4);
      acc0 += ((int)(v.x << 16)) >> 16;
      acc1 += ((int)v.x) >> 16;
      acc2 += ((int)(v.y << 16)) >> 16;
      acc3 += ((int)v.y) >> 16;
    }
  }
  for (; i < end; ++i) {
    int sj = srcSorted[i];
    uint2 v = *(const uint2*)(y1l + (size_t)sj * H + q * 4);
    acc0 += ((int)(v.x << 16)) >> 16;
    acc1 += ((int)v.x) >> 16;
    acc2 += ((int)(v.y << 16)) >> 16;
    acc3 += ((int)v.y) >> 16;
  }
  float s = (1.f / fmaxf((float)dg, 1.f)) * QINV;
  float4 yr = *(const float4*)(y1r + (size_t)n * H + q * 4);
  float4 bb = *(const float4*)(b1 + q * 4);
  float h1x = fmaxf(fmaf((float)acc0, s, bb.x + yr.x), 0.f);
  float h1y = fmaxf(fmaf((float)acc1, s, bb.y + yr.y), 0.f);
  float h1z = fmaxf(fmaf((float)acc2, s, bb.z + yr.z), 0.f);
  float h1w = fmaxf(fmaf((float)acc3, s, bb.w + yr.w), 0.f);
  float zl0 = 0.f, zl1 = 0.f, zl2 = 0.f, zl3 = 0.f;
  float zr0 = 0.f, zr1 = 0.f, zr2 = 0.f, zr3 = 0.f;
#pragma unroll
  for (int sl = 0; sl < 4; ++sl) {
    float hx = __shfl(h1x, sl, 4);
    float hy = __shfl(h1y, sl, 4);
    float hz = __shfl(h1z, sl, 4);
    float hw = __shfl(h1w, sl, 4);
    float hk4[4] = {hx, hy, hz, hw};
#pragma unroll
    for (int j = 0; j < 4; ++j) {
      int k = sl * 4 + j;               // h1 channel index
      float4 wl = *(const float4*)(W2l + k * H + q * 4);
      float4 wr = *(const float4*)(W2r + k * H + q * 4);
      float hk = hk4[j];
      zl0 = fmaf(hk, wl.x, zl0); zl1 = fmaf(hk, wl.y, zl1);
      zl2 = fmaf(hk, wl.z, zl2); zl3 = fmaf(hk, wl.w, zl3);
      zr0 = fmaf(hk, wr.x, zr0); zr1 = fmaf(hk, wr.y, zr1);
      zr2 = fmaf(hk, wr.z, zr2); zr3 = fmaf(hk, wr.w, zr3);
    }
  }
  uint2 pk;
  pk.x = packi16(zl0, zl1);
  pk.y = packi16(zl2, zl3);
  *(uint2*)(z2l + (size_t)n * H + q * 4) = pk;
  *(float4*)(z2r + (size_t)n * H + q * 4) = make_float4(zr0, zr1, zr2, zr3);
}

// ---------------------------------------------------------------------------
// gather2 (4 lanes/node): h2 = fp16(mean(z2l_nbrs) + b2 + z2r)
// ---------------------------------------------------------------------------
__global__ void __launch_bounds__(256) k_gather2(
    const int* __restrict__ srcSorted, const int* __restrict__ deg,
    const int* __restrict__ rowBeg, const unsigned short* __restrict__ z2l,
    const float* __restrict__ z2r, const float* __restrict__ b2,
    __half* __restrict__ h2) {
  int tid = blockIdx.x * 256 + threadIdx.x;
  int n = tid >> 2;
  int q = tid & 3;
  if (n >= N_NODES) return;
  int beg = rowBeg[n];
  int dg = deg[n];
  int end = beg + dg;
  int acc0 = 0, acc1 = 0, acc2 = 0, acc3 = 0;
  int i = beg;
  for (; i + 4 <= end; i += 4) {
    int sq = srcSorted[i + q];
#pragma unroll
    for (int j = 0; j < 4; ++j) {
      int sj = __shfl(sq, j, 4);
      uint2 v = *(const uint2*)(z2l + (size_t)sj * H + q * 4);
      acc0 += ((int)(v.x << 16)) >> 16;
      acc1 += ((int)v.x) >> 16;
      acc2 += ((int)(v.y << 16)) >> 16;
      acc3 += ((int)v.y) >> 16;
    }
  }
  for (; i < end; ++i) {
    int sj = srcSorted[i];
    uint2 v = *(const uint2*)(z2l + (size_t)sj * H + q * 4);
    acc0 += ((int)(v.x << 16)) >> 16;
    acc1 += ((int)v.x) >> 16;
    acc2 += ((int)(v.y << 16)) >> 16;
    acc3 += ((int)v.y) >> 16;
  }
  float s = (1.f / fmaxf((float)dg, 1.f)) * QINV;
  float4 zr = *(const float4*)(z2r + (size_t)n * H + q * 4);
  float4 bb = *(const float4*)(b2 + q * 4);
  float v0 = fmaf((float)acc0, s, bb.x + zr.x);
  float v1 = fmaf((float)acc1, s, bb.y + zr.y);
  float v2 = fmaf((float)acc2, s, bb.z + zr.z);
  float v3 = fmaf((float)acc3, s, bb.w + zr.w);
  __half2 h0 = __floats2half2_rn(v0, v1);
  __half2 h1 = __floats2half2_rn(v2, v3);
  uint2 pk;
  pk.x = *(unsigned int*)&h0;
  pk.y = *(unsigned int*)&h1;
  *(uint2*)(h2 + (size_t)n * H + q * 4) = pk;
}

// ---------------------------------------------------------------------------
// decode: out[p] = sigmoid(dot(h2[s], h2[d]))  — h2 rows are 32 B fp16
// ---------------------------------------------------------------------------
__device__ inline float dot8h(uint4 u, uint4 v) {
  float acc = 0.f;
  const unsigned int* uw = (const unsigned int*)&u;
  const unsigned int* vw = (const unsigned int*)&v;
#pragma unroll
  for (int j = 0; j < 4; ++j) {
    float2 a = __half22float2(*(const __half2*)&uw[j]);
    float2 b = __half22float2(*(const __half2*)&vw[j]);
    acc = fmaf(a.x, b.x, acc);
    acc = fmaf(a.y, b.y, acc);
  }
  return acc;
}

__global__ void __launch_bounds__(256) k_decode(
    const int* __restrict__ ps, const int* __restrict__ pd,
    const __half* __restrict__ h2, float* __restrict__ out, int P) {
  int p = blockIdx.x * 256 + threadIdx.x;
  if (p >= P) return;
  int a = ps[p];
  int b = pd[p];
  const uint4* ha = (const uint4*)(h2 + (size_t)a * H);  // 2x16B per row
  const uint4* hb = (const uint4*)(h2 + (size_t)b * H);
  uint4 u0 = ha[0], u1 = ha[1];
  uint4 v0 = hb[0], v1 = hb[1];
  float acc = dot8h(u0, v0) + dot8h(u1, v1);
  out[p] = 1.f / (1.f + __expf(-acc));
}

// ---------------------------------------------------------------------------
extern "C" void kernel_launch(void* const* d_in, const int* in_sizes, int n_in,
                              void* d_out, int out_size, void* d_ws, size_t ws_size,
                              hipStream_t stream) {
  const float* x   = (const float*)d_in[0];
  const float* W1l = (const float*)d_in[1];
  const float* b1  = (const float*)d_in[2];
  const float* W1r = (const float*)d_in[3];
  const float* W2l = (const float*)d_in[4];
  const float* b2  = (const float*)d_in[5];
  const float* W2r = (const float*)d_in[6];
  const int* ei = (const int*)d_in[7];  // [2, E] int32
  const int* di = (const int*)d_in[8];  // [2, P] int32
  const int E = in_sizes[7] / 2;
  const int P = in_sizes[8] / 2;

  const size_t NF = (size_t)N_NODES * H;
  // Gathered tables (3.2 MB each, L2-resident): y1l/z2l int16 fixed-point,
  // h2 fp16. h2 aliases y1l (dead after gather1). y1r fp32 aliases z2r
  // (same thread+element).
  unsigned short* y1l = (unsigned short*)d_ws;   // NF
  __half*         h2  = (__half*)y1l;            // alias
  unsigned short* z2l = y1l + NF;                // NF
  float*  y1r = (float*)(z2l + NF);              // NF floats
  float*  z2r = y1r;                             // alias
  int* recs   = (int*)(y1r + NF);                // NBIN * BINCAP
  int* binCur = recs + (size_t)NBIN * BINCAP;    // NBIN (padded to 512)
  int* deg    = binCur + 512;                    // N
  int* rowBeg = deg + N_NODES;                   // N

  const int lin1Blocks = (N_NODES + 127) / 128;   // 128 nodes per 256-thr block
  const int fillBlocks = (E + ECHUNK - 1) / ECHUNK;
  const int gatherBlocks = ((N_NODES * 4) + 255) / 256;   // 4 lanes/node

  k_init<<<1, 512, 0, stream>>>(binCur);
  k_lin1<<<lin1Blocks, 256, 0, stream>>>(x, W1l, W1r, y1l, y1r);
  k_binfill<<<fillBlocks, 512, 0, stream>>>(ei, ei + E, binCur, recs, E);
  k_group<<<NBIN, 512, 0, stream>>>(recs, binCur, deg, rowBeg);
  k_gather1<<<gatherBlocks, 256, 0, stream>>>(recs, deg, rowBeg, y1l, y1r,
                                              b1, W2l, W2r, z2l, z2r);
  k_gather2<<<gatherBlocks, 256, 0, stream>>>(recs, deg, rowBeg, z2l, z2r,
                                              b2, h2);
  k_decode<<<(P + 255) / 256, 256, 0, stream>>>(di, di + P, h2, (float*)d_out, P);
}